// Round 3
// baseline (23652.908 us; speedup 1.0000x reference)
//
#include <hip/hip_runtime.h>
#include <hip/hip_bf16.h>

#define T_STEPS 512
#define BATCH   64
#define HID     1024
#define NWG     64

typedef __attribute__((ext_vector_type(8))) short short8;
typedef __attribute__((ext_vector_type(4))) float f32x4;

static __device__ __forceinline__ float b2f(unsigned short u){
  union { unsigned u; float f; } c; c.u = ((unsigned)u) << 16; return c.f;
}
static __device__ __forceinline__ unsigned short f2b(float f){
  union { float f; unsigned u; } c; c.f = f;
  unsigned r = c.u + 0x7fffu + ((c.u >> 16) & 1u);
  return (unsigned short)(r >> 16);
}
static __device__ __forceinline__ float sigm(float x){ return 1.0f / (1.0f + __expf(-x)); }
static __device__ __forceinline__ float tanh_fast(float x){ return 2.0f / (1.0f + __expf(-2.0f * x)) - 1.0f; }

// coherent (L2-bypass) 16B fragment load from MALL: two 8B agent-relaxed atomics
static __device__ __forceinline__ short8 ldsc(const unsigned short* p){
  unsigned long long a = __hip_atomic_load((const unsigned long long*)p,
                                           __ATOMIC_RELAXED, __HIP_MEMORY_SCOPE_AGENT);
  unsigned long long b = __hip_atomic_load((const unsigned long long*)(p + 4),
                                           __ATOMIC_RELAXED, __HIP_MEMORY_SCOPE_AGENT);
  union { unsigned long long q[2]; short8 s; } u;
  u.q[0] = a; u.q[1] = b; return u.s;
}

// ---------------- init: zero barrier flags (coherent stores) ----------------
__global__ void gru_init_k(int* __restrict__ flags){
  int i = blockIdx.x * blockDim.x + threadIdx.x;
  if (i < NWG * 16)
    __hip_atomic_store(flags + i, 0, __ATOMIC_RELAXED, __HIP_MEMORY_SCOPE_AGENT);
}

// ---------------- cast inputs fp32 -> bf16 ----------------
__global__ void gru_castx_k(const float4* __restrict__ in, unsigned short* __restrict__ out, int n4){
  int stride = gridDim.x * blockDim.x;
  for (int i = blockIdx.x * blockDim.x + threadIdx.x; i < n4; i += stride){
    float4 v = in[i];
    ushort4 o;
    o.x = f2b(v.x); o.y = f2b(v.y); o.z = f2b(v.z); o.w = f2b(v.w);
    *(ushort4*)(out + (size_t)i * 4) = o;
  }
}

// ---------------- transpose + cast weights: Wt[g][n][k] = W_g[k][n] ----------------
__global__ void gru_prepw_k(const float* __restrict__ w0, const float* __restrict__ w1,
                            const float* __restrict__ w2, const float* __restrict__ w3,
                            const float* __restrict__ w4, const float* __restrict__ w5,
                            unsigned short* __restrict__ wt){
  __shared__ float tile[32][33];
  const float* src;
  switch (blockIdx.z){
    case 0: src = w0; break; case 1: src = w1; break; case 2: src = w2; break;
    case 3: src = w3; break; case 4: src = w4; break; default: src = w5; break;
  }
  int tx = threadIdx.x, ty = threadIdx.y;
  int x0 = blockIdx.x * 32, y0 = blockIdx.y * 32;
  #pragma unroll
  for (int i = 0; i < 32; i += 8)
    tile[ty + i][tx] = src[(size_t)(y0 + ty + i) * HID + x0 + tx];
  __syncthreads();
  unsigned short* dst = wt + (size_t)blockIdx.z * HID * HID;
  #pragma unroll
  for (int i = 0; i < 32; i += 8)
    dst[(size_t)(x0 + ty + i) * HID + y0 + tx] = f2b(tile[tx][ty + i]);
}

// ---------------- wave-0-only flag poll (no cache fence; data reads are coherent) ----
static __device__ __forceinline__ void waitflags(const int* flags, int target){
  int lane = threadIdx.x & 63;
  for (;;){
    int v = __hip_atomic_load(flags + lane * 16, __ATOMIC_RELAXED, __HIP_MEMORY_SCOPE_AGENT);
    if (__all(v >= target)) return;
  }
}

#define MFMA __builtin_amdgcn_mfma_f32_16x16x32_bf16

// ---------------- persistent GRU scan ----------------
__global__ __launch_bounds__(512, 1) void gru_scan_k(
    const unsigned short* __restrict__ xbf,   // [T][64][1024] bf16
    const unsigned short* __restrict__ wt,    // [6][1024][1024] bf16, [n][k]
    const float* __restrict__ bz, const float* __restrict__ br, const float* __restrict__ bh,
    float* __restrict__ out,                  // [T][64][1024] fp32 + [64][1024] H_final
    unsigned short* __restrict__ hbf,         // [64][1024] bf16 H state (coherent)
    unsigned short* __restrict__ rhbf,        // [64][1024] bf16 R*H     (coherent)
    int* __restrict__ flags)
{
  // recurrent weights in MFMA fragment order: wl[mat][k/32][lane][8]
  __shared__ unsigned short wl[3 * 32 * 64 * 8];   // 96 KiB
  __shared__ float hlds[BATCH * 16];               // this WG's H tile fp32 [row][l16]
  __shared__ float pbuf[BATCH * 16];               // split-K partials for H_tilde

  const int wg   = blockIdx.x;
  const int tid  = threadIdx.x;
  const int wave = tid >> 6;
  const int lane = tid & 63;
  const int l16  = lane & 15;
  const int kq   = lane >> 4;
  const int rb   = wave & 3;
  const bool zp  = (wave < 4);       // waves 0-3: Z + H_tilde; 4-7: R + split-K help
  const int col  = wg * 16 + l16;
  const int arow = rb * 16 + l16;
  const int crow0 = rb * 16 + kq * 4;

  // stage Whz(1), Whr(3), Whh(5) in fragment order (contiguous 1KB per wave read)
  for (int idx = tid; idx < 3 * 32 * 64; idx += 512){
    int mat = idx / (32 * 64), rem = idx % (32 * 64), kk5 = rem >> 6, ln = rem & 63;
    int n = ln & 15, kq2 = ln >> 4;
    *(short8*)&wl[(size_t)idx * 8] =
      *(const short8*)&wt[(size_t)(2 * mat + 1) * HID * HID +
                          (size_t)(wg * 16 + n) * HID + (size_t)(kk5 * 32 + kq2 * 8)];
  }
  for (int idx = tid; idx < BATCH * 16; idx += 512){ hlds[idx] = 0.f; pbuf[idx] = 0.f; }

  // per-lane LDS fragment bases: frag for K-offset kk lives at base + kk*16 shorts
  const unsigned short* wlg = wl + ((size_t)(zp ? 0 : 1) * 32 * 64 + lane) * 8;
  const unsigned short* wlh = wl + ((size_t)2 * 32 * 64 + lane) * 8;

  const unsigned short* wxg = wt + (size_t)(zp ? 0 : 2) * HID * HID + (size_t)col * HID + kq * 8;
  const unsigned short* wxh = wt + (size_t)4 * HID * HID + (size_t)col * HID + kq * 8;
  const unsigned short* hrow  = hbf  + (size_t)arow * HID + kq * 8;
  const unsigned short* rhrow = rhbf + (size_t)arow * HID + kq * 8;
  const float bg  = (zp ? bz : br)[col];
  const float bhv = bh[col];

  float h[4] = {0.f, 0.f, 0.f, 0.f};
  float gate[4];

  __syncthreads();

  for (int t = 0; t < T_STEPS; ++t){
    const unsigned short* xrow = xbf + ((size_t)t * BATCH + arow) * HID + kq * 8;

    // ---- phase A: x-part (cached loads, hides the wait), 2 acc chains ----
    f32x4 a0 = {0.f,0.f,0.f,0.f}, a1 = {0.f,0.f,0.f,0.f};
    #pragma unroll 4
    for (int kk = 0; kk < HID; kk += 64){
      a0 = MFMA(*(const short8*)(xrow + kk),      *(const short8*)(wxg + kk),      a0, 0,0,0);
      a1 = MFMA(*(const short8*)(xrow + kk + 32), *(const short8*)(wxg + kk + 32), a1, 0,0,0);
    }
    if (wave == 0 && t) waitflags(flags, 2 * t);
    __syncthreads();
    if (t){
      #pragma unroll 4
      for (int kk = 0; kk < HID; kk += 64){
        a0 = MFMA(ldsc(hrow + kk),      *(const short8*)(wlg + (size_t)kk * 16),        a0, 0,0,0);
        a1 = MFMA(ldsc(hrow + kk + 32), *(const short8*)(wlg + (size_t)(kk + 32) * 16), a1, 0,0,0);
      }
    }
    if (zp){
      #pragma unroll
      for (int j = 0; j < 4; ++j) gate[j] = sigm(a0[j] + a1[j] + bg);      // Z
    } else {
      #pragma unroll
      for (int j = 0; j < 4; ++j){
        float hp = hlds[(crow0 + j) * 16 + l16];
        float r  = sigm(a0[j] + a1[j] + bg);                               // R
        __builtin_nontemporal_store(f2b(r * hp), &rhbf[(size_t)(crow0 + j) * HID + col]);
      }
    }
    __syncthreads();   // drains stores (vmcnt) before release
    if (tid == 0)
      __hip_atomic_store(&flags[wg * 16], 2 * t + 1, __ATOMIC_RELEASE, __HIP_MEMORY_SCOPE_AGENT);

    // ---- phase B: H_tilde; xh before the wait; RH-part split-K across all 8 waves ----
    f32x4 c0 = {0.f,0.f,0.f,0.f}, c1 = {0.f,0.f,0.f,0.f};
    if (zp){
      #pragma unroll 4
      for (int kk = 0; kk < HID; kk += 64){
        c0 = MFMA(*(const short8*)(xrow + kk),      *(const short8*)(wxh + kk),      c0, 0,0,0);
        c1 = MFMA(*(const short8*)(xrow + kk + 32), *(const short8*)(wxh + kk + 32), c1, 0,0,0);
      }
    }
    if (wave == 0) waitflags(flags, 2 * t + 1);
    __syncthreads();
    {
      const int k0 = zp ? 0 : 512;
      #pragma unroll 4
      for (int kk = 0; kk < 512; kk += 64){
        c0 = MFMA(ldsc(rhrow + k0 + kk),      *(const short8*)(wlh + (size_t)(k0 + kk) * 16),      c0, 0,0,0);
        c1 = MFMA(ldsc(rhrow + k0 + kk + 32), *(const short8*)(wlh + (size_t)(k0 + kk + 32) * 16), c1, 0,0,0);
      }
    }
    if (!zp){
      #pragma unroll
      for (int j = 0; j < 4; ++j) pbuf[(crow0 + j) * 16 + l16] = c0[j] + c1[j];
    }
    __syncthreads();
    if (zp){
      #pragma unroll
      for (int j = 0; j < 4; ++j){
        float ht = tanh_fast(c0[j] + c1[j] + pbuf[(crow0 + j) * 16 + l16] + bhv);
        float hn = gate[j] * h[j] + (1.0f - gate[j]) * ht;
        h[j] = hn;
        hlds[(crow0 + j) * 16 + l16] = hn;
        __builtin_nontemporal_store(f2b(hn), &hbf[(size_t)(crow0 + j) * HID + col]);
      }
    }
    __syncthreads();   // hbf stores drained before release
    if (tid == 0)
      __hip_atomic_store(&flags[wg * 16], 2 * t + 2, __ATOMIC_RELEASE, __HIP_MEMORY_SCOPE_AGENT);
    if (zp){
      #pragma unroll
      for (int j = 0; j < 4; ++j){
        __builtin_nontemporal_store(h[j], &out[((size_t)t * BATCH + crow0 + j) * HID + col]);
        if (t == T_STEPS - 1)
          __builtin_nontemporal_store(h[j],
              &out[(size_t)T_STEPS * BATCH * HID + (size_t)(crow0 + j) * HID + col]);
      }
    }
  }
}

extern "C" void kernel_launch(void* const* d_in, const int* in_sizes, int n_in,
                              void* d_out, int out_size, void* d_ws, size_t ws_size,
                              hipStream_t stream){
  const float* inputs = (const float*)d_in[0];
  const float* W_xz = (const float*)d_in[1];
  const float* W_hz = (const float*)d_in[2];
  const float* b_z  = (const float*)d_in[3];
  const float* W_xr = (const float*)d_in[4];
  const float* W_hr = (const float*)d_in[5];
  const float* b_r  = (const float*)d_in[6];
  const float* W_xh = (const float*)d_in[7];
  const float* W_hh = (const float*)d_in[8];
  const float* b_h  = (const float*)d_in[9];
  float* out = (float*)d_out;

  char* ws = (char*)d_ws;
  int*            flags = (int*)ws;                                  // 4 KiB
  unsigned short* hbf   = (unsigned short*)(ws + 4096);              // 128 KiB
  unsigned short* rhbf  = (unsigned short*)(ws + 4096 + 131072);     // 128 KiB
  unsigned short* wt    = (unsigned short*)(ws + 266240);            // 12 MiB
  unsigned short* xbf   = (unsigned short*)(ws + 266240 + 12582912); // 64 MiB
  // total ws needed: ~76.3 MB

  gru_init_k<<<4, 256, 0, stream>>>(flags);
  gru_castx_k<<<2048, 256, 0, stream>>>((const float4*)inputs, xbf, T_STEPS * BATCH * HID / 4);
  gru_prepw_k<<<dim3(32, 32, 6), dim3(32, 8), 0, stream>>>(W_xz, W_hz, W_xr, W_hr, W_xh, W_hh, wt);
  gru_scan_k<<<NWG, 512, 0, stream>>>(xbf, wt, b_z, b_r, b_h, out, hbf, rhbf, flags);
}

// Round 4
// 22708.295 us; speedup vs baseline: 1.0416x; 1.0416x over previous
//
#include <hip/hip_runtime.h>
#include <hip/hip_bf16.h>

#define T_STEPS 512
#define BATCH   64
#define HID     1024
#define NWG     64

typedef __attribute__((ext_vector_type(8))) short short8;
typedef __attribute__((ext_vector_type(4))) float f32x4;

static __device__ __forceinline__ unsigned short f2b(float f){
  union { float f; unsigned u; } c; c.f = f;
  unsigned r = c.u + 0x7fffu + ((c.u >> 16) & 1u);
  return (unsigned short)(r >> 16);
}
static __device__ __forceinline__ float sigm(float x){ return 1.0f / (1.0f + __expf(-x)); }
static __device__ __forceinline__ float tanh_fast(float x){ return 2.0f / (1.0f + __expf(-2.0f * x)) - 1.0f; }

// coherent (L2-bypass) 16B fragment load from MALL: two 8B agent-relaxed atomics
static __device__ __forceinline__ short8 ldsc(const unsigned short* p){
  unsigned long long a = __hip_atomic_load((const unsigned long long*)p,
                                           __ATOMIC_RELAXED, __HIP_MEMORY_SCOPE_AGENT);
  unsigned long long b = __hip_atomic_load((const unsigned long long*)(p + 4),
                                           __ATOMIC_RELAXED, __HIP_MEMORY_SCOPE_AGENT);
  union { unsigned long long q[2]; short8 s; } u;
  u.q[0] = a; u.q[1] = b; return u.s;
}

// ---------------- init: zero barrier flags (coherent stores) ----------------
__global__ void gru_init_k(int* __restrict__ flags){
  int i = blockIdx.x * blockDim.x + threadIdx.x;
  if (i < NWG * 16)
    __hip_atomic_store(flags + i, 0, __ATOMIC_RELAXED, __HIP_MEMORY_SCOPE_AGENT);
}

// ---------------- cast inputs fp32 -> bf16 ----------------
__global__ void gru_castx_k(const float4* __restrict__ in, unsigned short* __restrict__ out, int n4){
  int stride = gridDim.x * blockDim.x;
  for (int i = blockIdx.x * blockDim.x + threadIdx.x; i < n4; i += stride){
    float4 v = in[i];
    ushort4 o;
    o.x = f2b(v.x); o.y = f2b(v.y); o.z = f2b(v.z); o.w = f2b(v.w);
    *(ushort4*)(out + (size_t)i * 4) = o;
  }
}

// ---------------- transpose + cast weights: Wt[g][n][k] = W_g[k][n] ----------------
__global__ void gru_prepw_k(const float* __restrict__ w0, const float* __restrict__ w1,
                            const float* __restrict__ w2, const float* __restrict__ w3,
                            const float* __restrict__ w4, const float* __restrict__ w5,
                            unsigned short* __restrict__ wt){
  __shared__ float tile[32][33];
  const float* src;
  switch (blockIdx.z){
    case 0: src = w0; break; case 1: src = w1; break; case 2: src = w2; break;
    case 3: src = w3; break; case 4: src = w4; break; default: src = w5; break;
  }
  int tx = threadIdx.x, ty = threadIdx.y;
  int x0 = blockIdx.x * 32, y0 = blockIdx.y * 32;
  #pragma unroll
  for (int i = 0; i < 32; i += 8)
    tile[ty + i][tx] = src[(size_t)(y0 + ty + i) * HID + x0 + tx];
  __syncthreads();
  unsigned short* dst = wt + (size_t)blockIdx.z * HID * HID;
  #pragma unroll
  for (int i = 0; i < 32; i += 8)
    dst[(size_t)(x0 + ty + i) * HID + y0 + tx] = f2b(tile[tx][ty + i]);
}

// ---------------- wave-0-only flag poll (no cache fence anywhere) ----------------
static __device__ __forceinline__ void waitflags(const int* flags, int target){
  int lane = threadIdx.x & 63;
  for (;;){
    int v = __hip_atomic_load(flags + lane * 16, __ATOMIC_RELAXED, __HIP_MEMORY_SCOPE_AGENT);
    if (__all(v >= target)) return;
  }
}

#define MFMA __builtin_amdgcn_mfma_f32_16x16x32_bf16

// ---------------- persistent GRU scan ----------------
__global__ __launch_bounds__(512, 1) void gru_scan_k(
    const unsigned short* __restrict__ xbf,   // [T][64][1024] bf16
    const unsigned short* __restrict__ wt,    // [6][1024][1024] bf16, [n][k]
    const float* __restrict__ bz, const float* __restrict__ br, const float* __restrict__ bh,
    float* __restrict__ out,                  // [T][64][1024] fp32 + [64][1024] H_final
    unsigned short* __restrict__ hb2,         // [128][64][8] bf16 H, fragment-major (MALL)
    unsigned short* __restrict__ rh2,         // [128][64][8] bf16 R*H, fragment-major (MALL)
    int* __restrict__ flags)
{
  // recurrent weights in MFMA fragment order: wl[mat][k/32][lane][8]
  __shared__ unsigned short wl[3 * 32 * 64 * 8];   // 96 KiB
  __shared__ float hlds[BATCH * 16];               // this WG's H tile fp32 [row][l16]

  const int wg   = blockIdx.x;
  const int tid  = threadIdx.x;
  const int wave = tid >> 6;
  const int lane = tid & 63;
  const int l16  = lane & 15;
  const int kq   = lane >> 4;
  const int rb   = wave & 3;
  const bool zp  = (wave < 4);       // waves 0-3: Z + H_tilde; waves 4-7: R
  const int col  = wg * 16 + l16;
  const int arow = rb * 16 + l16;
  const int crow0 = rb * 16 + kq * 4;

  // stage Whz(1), Whr(3), Whh(5) in fragment order (contiguous 1KB per wave read)
  for (int idx = tid; idx < 3 * 32 * 64; idx += 512){
    int mat = idx / (32 * 64), rem = idx % (32 * 64), kk5 = rem >> 6, ln = rem & 63;
    int n = ln & 15, kq2 = ln >> 4;
    *(short8*)&wl[(size_t)idx * 8] =
      *(const short8*)&wt[(size_t)(2 * mat + 1) * HID * HID +
                          (size_t)(wg * 16 + n) * HID + (size_t)(kk5 * 32 + kq2 * 8)];
  }
  for (int idx = tid; idx < BATCH * 16; idx += 512) hlds[idx] = 0.f;

  // per-lane LDS weight fragment bases: fragment for K-offset 32i at base + 512*i shorts
  const unsigned short* wlg = wl + ((size_t)(zp ? 0 : 1) * 32 * 64 + lane) * 8;
  const unsigned short* wlh = wl + ((size_t)2 * 32 * 64 + lane) * 8;

  // A-operand fragment bases in fragment-major shared buffers (stride 2048 per 32-k)
  const unsigned short* hfr = hb2 + (size_t)arow * 8 + (size_t)kq * 512;
  const unsigned short* rfr = rh2 + (size_t)arow * 8 + (size_t)kq * 512;

  const unsigned short* wxg = wt + (size_t)(zp ? 0 : 2) * HID * HID + (size_t)col * HID + kq * 8;
  const unsigned short* wxh = wt + (size_t)4 * HID * HID + (size_t)col * HID + kq * 8;
  const float bg  = (zp ? bz : br)[col];
  const float bhv = bh[col];

  // producer store indexing (fragment-major): elem (row, col) at ((col>>3)*64+row)*8+(col&7)
  // lane pairs (even/odd l16) pack two adjacent cols into one 4B atomic store
  const bool evn = (l16 & 1) == 0;

  float h[4] = {0.f, 0.f, 0.f, 0.f};
  float gate[4];

  __syncthreads();

  for (int t = 0; t < T_STEPS; ++t){
    const unsigned short* xrow = xbf + ((size_t)t * BATCH + arow) * HID + kq * 8;

    // ---- phase A: x-part (cached, hides the wait), 2 acc chains ----
    f32x4 a0 = {0.f,0.f,0.f,0.f}, a1 = {0.f,0.f,0.f,0.f};
    #pragma unroll 4
    for (int kk = 0; kk < HID; kk += 64){
      a0 = MFMA(*(const short8*)(xrow + kk),      *(const short8*)(wxg + kk),      a0, 0,0,0);
      a1 = MFMA(*(const short8*)(xrow + kk + 32), *(const short8*)(wxg + kk + 32), a1, 0,0,0);
    }
    if (wave == 0 && t) waitflags(flags, 2 * t);
    __syncthreads();
    if (t){
      short8 hf[32];
      #pragma unroll
      for (int i = 0; i < 32; ++i) hf[i] = ldsc(hfr + (size_t)i * 2048);  // batch-issue, 1 RTT
      #pragma unroll
      for (int i = 0; i < 32; i += 2){
        a0 = MFMA(hf[i],     *(const short8*)(wlg + (size_t)i * 512),       a0, 0,0,0);
        a1 = MFMA(hf[i + 1], *(const short8*)(wlg + (size_t)(i + 1) * 512), a1, 0,0,0);
      }
    }
    if (zp){
      #pragma unroll
      for (int j = 0; j < 4; ++j) gate[j] = sigm(a0[j] + a1[j] + bg);      // Z
    } else {
      #pragma unroll
      for (int j = 0; j < 4; ++j){
        float hp = hlds[(crow0 + j) * 16 + l16];
        unsigned v = f2b(sigm(a0[j] + a1[j] + bg) * hp);                   // R*H bf16
        unsigned o = __shfl_xor((int)v, 1);
        if (evn)
          __hip_atomic_store((unsigned*)&rh2[((size_t)(col >> 3) * 64 + crow0 + j) * 8 + (col & 7)],
                             v | (o << 16), __ATOMIC_RELAXED, __HIP_MEMORY_SCOPE_AGENT);
      }
    }
    __syncthreads();   // each wave drains its stores (vmcnt) before leader releases
    if (tid == 0){
      asm volatile("s_waitcnt vmcnt(0)" ::: "memory");
      __hip_atomic_store(&flags[wg * 16], 2 * t + 1, __ATOMIC_RELAXED, __HIP_MEMORY_SCOPE_AGENT);
    }

    // ---- phase B (zp waves): H_tilde; xh part before the wait ----
    f32x4 c0 = {0.f,0.f,0.f,0.f}, c1 = {0.f,0.f,0.f,0.f};
    if (zp){
      #pragma unroll 4
      for (int kk = 0; kk < HID; kk += 64){
        c0 = MFMA(*(const short8*)(xrow + kk),      *(const short8*)(wxh + kk),      c0, 0,0,0);
        c1 = MFMA(*(const short8*)(xrow + kk + 32), *(const short8*)(wxh + kk + 32), c1, 0,0,0);
      }
    }
    if (wave == 0) waitflags(flags, 2 * t + 1);
    __syncthreads();
    if (zp){
      short8 rf[32];
      #pragma unroll
      for (int i = 0; i < 32; ++i) rf[i] = ldsc(rfr + (size_t)i * 2048);
      #pragma unroll
      for (int i = 0; i < 32; i += 2){
        c0 = MFMA(rf[i],     *(const short8*)(wlh + (size_t)i * 512),       c0, 0,0,0);
        c1 = MFMA(rf[i + 1], *(const short8*)(wlh + (size_t)(i + 1) * 512), c1, 0,0,0);
      }
      #pragma unroll
      for (int j = 0; j < 4; ++j){
        float ht = tanh_fast(c0[j] + c1[j] + bhv);
        float hn = gate[j] * h[j] + (1.0f - gate[j]) * ht;
        h[j] = hn;
        hlds[(crow0 + j) * 16 + l16] = hn;
        unsigned v = (unsigned)f2b(hn);
        unsigned o = __shfl_xor((int)v, 1);
        if (evn)
          __hip_atomic_store((unsigned*)&hb2[((size_t)(col >> 3) * 64 + crow0 + j) * 8 + (col & 7)],
                             v | (o << 16), __ATOMIC_RELAXED, __HIP_MEMORY_SCOPE_AGENT);
      }
    }
    __syncthreads();   // hb2 stores drained before release
    if (tid == 0){
      asm volatile("s_waitcnt vmcnt(0)" ::: "memory");
      __hip_atomic_store(&flags[wg * 16], 2 * t + 2, __ATOMIC_RELAXED, __HIP_MEMORY_SCOPE_AGENT);
    }
    if (zp){   // out stores off the critical path, never read by other WGs
      #pragma unroll
      for (int j = 0; j < 4; ++j){
        __builtin_nontemporal_store(h[j], &out[((size_t)t * BATCH + crow0 + j) * HID + col]);
        if (t == T_STEPS - 1)
          __builtin_nontemporal_store(h[j],
              &out[(size_t)T_STEPS * BATCH * HID + (size_t)(crow0 + j) * HID + col]);
      }
    }
  }
}

extern "C" void kernel_launch(void* const* d_in, const int* in_sizes, int n_in,
                              void* d_out, int out_size, void* d_ws, size_t ws_size,
                              hipStream_t stream){
  const float* inputs = (const float*)d_in[0];
  const float* W_xz = (const float*)d_in[1];
  const float* W_hz = (const float*)d_in[2];
  const float* b_z  = (const float*)d_in[3];
  const float* W_xr = (const float*)d_in[4];
  const float* W_hr = (const float*)d_in[5];
  const float* b_r  = (const float*)d_in[6];
  const float* W_xh = (const float*)d_in[7];
  const float* W_hh = (const float*)d_in[8];
  const float* b_h  = (const float*)d_in[9];
  float* out = (float*)d_out;

  char* ws = (char*)d_ws;
  int*            flags = (int*)ws;                                  // 4 KiB
  unsigned short* hb2   = (unsigned short*)(ws + 4096);              // 128 KiB
  unsigned short* rh2   = (unsigned short*)(ws + 4096 + 131072);     // 128 KiB
  unsigned short* wt    = (unsigned short*)(ws + 266240);            // 12 MiB
  unsigned short* xbf   = (unsigned short*)(ws + 266240 + 12582912); // 64 MiB
  // total ws needed: ~76.3 MB

  gru_init_k<<<4, 256, 0, stream>>>(flags);
  gru_castx_k<<<2048, 256, 0, stream>>>((const float4*)inputs, xbf, T_STEPS * BATCH * HID / 4);
  gru_prepw_k<<<dim3(32, 32, 6), dim3(32, 8), 0, stream>>>(W_xz, W_hz, W_xr, W_hr, W_xh, W_hh, wt);
  gru_scan_k<<<NWG, 512, 0, stream>>>(xbf, wt, b_z, b_r, b_h, out, hb2, rh2, flags);
}

// Round 5
// 14630.606 us; speedup vs baseline: 1.6167x; 1.5521x over previous
//
#include <hip/hip_runtime.h>
#include <hip/hip_bf16.h>

#define T_STEPS 512
#define BATCH   64
#define HID     1024
#define NWG     64

typedef __attribute__((ext_vector_type(8))) short short8;
typedef __attribute__((ext_vector_type(4))) float f32x4;

static __device__ __forceinline__ float b2f(unsigned short u){
  union { unsigned u; float f; } c; c.u = ((unsigned)u) << 16; return c.f;
}
static __device__ __forceinline__ unsigned short f2b(float f){
  union { float f; unsigned u; } c; c.f = f;
  unsigned r = c.u + 0x7fffu + ((c.u >> 16) & 1u);
  return (unsigned short)(r >> 16);
}
static __device__ __forceinline__ float sigm(float x){ return 1.0f / (1.0f + __expf(-x)); }
static __device__ __forceinline__ float tanh_fast(float x){ return 2.0f / (1.0f + __expf(-2.0f * x)) - 1.0f; }

// coherent (L2-bypass) 16B fragment load from MALL: two 8B agent-relaxed atomics
static __device__ __forceinline__ short8 ldsc(const unsigned short* p){
  unsigned long long a = __hip_atomic_load((const unsigned long long*)p,
                                           __ATOMIC_RELAXED, __HIP_MEMORY_SCOPE_AGENT);
  unsigned long long b = __hip_atomic_load((const unsigned long long*)(p + 4),
                                           __ATOMIC_RELAXED, __HIP_MEMORY_SCOPE_AGENT);
  union { unsigned long long q[2]; short8 s; } u;
  u.q[0] = a; u.q[1] = b; return u.s;
}

#define MFMA __builtin_amdgcn_mfma_f32_16x16x32_bf16

// ---------------- init: zero barrier flags ----------------
__global__ void gru_init_k(int* __restrict__ flags){
  int i = blockIdx.x * blockDim.x + threadIdx.x;
  if (i < NWG)
    __hip_atomic_store(flags + i, 0, __ATOMIC_RELAXED, __HIP_MEMORY_SCOPE_AGENT);
}

// ---------------- transpose + cast weights: Wt[g][n][k] = W_g[k][n] ----------------
__global__ void gru_prepw_k(const float* __restrict__ w0, const float* __restrict__ w1,
                            const float* __restrict__ w2, const float* __restrict__ w3,
                            const float* __restrict__ w4, const float* __restrict__ w5,
                            unsigned short* __restrict__ wt){
  __shared__ float tile[32][33];
  const float* src;
  switch (blockIdx.z){
    case 0: src = w0; break; case 1: src = w1; break; case 2: src = w2; break;
    case 3: src = w3; break; case 4: src = w4; break; default: src = w5; break;
  }
  int tx = threadIdx.x, ty = threadIdx.y;
  int x0 = blockIdx.x * 32, y0 = blockIdx.y * 32;
  #pragma unroll
  for (int i = 0; i < 32; i += 8)
    tile[ty + i][tx] = src[(size_t)(y0 + ty + i) * HID + x0 + tx];
  __syncthreads();
  unsigned short* dst = wt + (size_t)blockIdx.z * HID * HID;
  #pragma unroll
  for (int i = 0; i < 32; i += 8)
    dst[(size_t)(x0 + ty + i) * HID + y0 + tx] = f2b(tile[tx][ty + i]);
}

// ---------------- pre-pass: G[m][3*1024] = X @ [Wxz|Wxr|Wxh] + bias (bf16) ----------
// M = T*B = 32768, K = 1024. Tile: 64 rows x 256 cols, 4 waves (each 64x64).
__global__ __launch_bounds__(256, 2) void gru_xproj_k(
    const float* __restrict__ inp,         // [32768][1024] fp32
    const unsigned short* __restrict__ wt, // [6][1024][1024] bf16 [n][k]; x-weights slots 0,2,4
    const float* __restrict__ bz, const float* __restrict__ br, const float* __restrict__ bh,
    unsigned short* __restrict__ G)        // [32768][3072] bf16
{
  const int wv = threadIdx.x >> 6, lane = threadIdx.x & 63;
  const int l16 = lane & 15, kq = lane >> 4;
  const int m0 = blockIdx.x * 64;
  const int n0 = blockIdx.y * 256 + wv * 64;

  // per-col-tile weight base + bias (gate constant within a 16-col tile)
  const unsigned short* wb[4];
  float bias[4];
  #pragma unroll
  for (int c = 0; c < 4; ++c){
    int n = n0 + c * 16 + l16;
    int g = n >> 10, cc = n & 1023;
    wb[c] = wt + (size_t)(2 * g) * HID * HID + (size_t)cc * HID + kq * 8;
    bias[c] = (g == 0 ? bz : (g == 1 ? br : bh))[cc];
  }
  const float* arow[4];
  #pragma unroll
  for (int r = 0; r < 4; ++r)
    arow[r] = inp + (size_t)(m0 + r * 16 + l16) * HID + kq * 8;

  f32x4 acc[4][4];
  #pragma unroll
  for (int r = 0; r < 4; ++r)
    #pragma unroll
    for (int c = 0; c < 4; ++c) acc[r][c] = (f32x4){0.f,0.f,0.f,0.f};

  #pragma unroll 2
  for (int kk = 0; kk < HID; kk += 32){
    short8 af[4], bf[4];
    #pragma unroll
    for (int r = 0; r < 4; ++r){
      float4 f0 = *(const float4*)(arow[r] + kk);
      float4 f1 = *(const float4*)(arow[r] + kk + 4);
      short8 a;
      a[0]=(short)f2b(f0.x); a[1]=(short)f2b(f0.y); a[2]=(short)f2b(f0.z); a[3]=(short)f2b(f0.w);
      a[4]=(short)f2b(f1.x); a[5]=(short)f2b(f1.y); a[6]=(short)f2b(f1.z); a[7]=(short)f2b(f1.w);
      af[r] = a;
    }
    #pragma unroll
    for (int c = 0; c < 4; ++c) bf[c] = *(const short8*)(wb[c] + kk);
    #pragma unroll
    for (int r = 0; r < 4; ++r)
      #pragma unroll
      for (int c = 0; c < 4; ++c)
        acc[r][c] = MFMA(af[r], bf[c], acc[r][c], 0, 0, 0);
  }

  #pragma unroll
  for (int c = 0; c < 4; ++c){
    int n = n0 + c * 16 + l16;
    #pragma unroll
    for (int r = 0; r < 4; ++r){
      int mrow = m0 + r * 16 + kq * 4;
      #pragma unroll
      for (int j = 0; j < 4; ++j)
        G[(size_t)(mrow + j) * 3072 + n] = f2b(acc[r][c][j] + bias[c]);
    }
  }
}

// ---------------- wave-0-only flag poll (flags packed in 256 B) ----------------
static __device__ __forceinline__ void waitflags(const int* flags, int target){
  int lane = threadIdx.x & 63;
  for (;;){
    int v = __hip_atomic_load(flags + lane, __ATOMIC_RELAXED, __HIP_MEMORY_SCOPE_AGENT);
    if (__all(v >= target)) return;
  }
}

// ---------------- persistent GRU scan (recurrent part only) ----------------
__global__ __launch_bounds__(512, 1) void gru_scan_k(
    const unsigned short* __restrict__ G,     // [32768][3072] bf16 precomputed x-gates
    const unsigned short* __restrict__ wt,    // [6][1024][1024] bf16 [n][k]
    float* __restrict__ out,                  // [T][64][1024] fp32 + [64][1024] H_final
    unsigned short* __restrict__ hb2,         // [128][64][8] bf16 H, fragment-major (MALL)
    unsigned short* __restrict__ rh2,         // [128][64][8] bf16 R*H, fragment-major (MALL)
    int* __restrict__ flags)
{
  // recurrent weights in MFMA fragment order: wl[mat][k/32][lane][8]
  __shared__ unsigned short wl[3 * 32 * 64 * 8];   // 96 KiB
  __shared__ float hlds[BATCH * 16];               // this WG's H tile fp32 [row][l16]

  const int wg   = blockIdx.x;
  const int tid  = threadIdx.x;
  const int wave = tid >> 6;
  const int lane = tid & 63;
  const int l16  = lane & 15;
  const int kq   = lane >> 4;
  const int rb   = wave & 3;
  const bool zp  = (wave < 4);       // waves 0-3: Z + H_tilde; waves 4-7: R
  const int col  = wg * 16 + l16;
  const int arow = rb * 16 + l16;
  const int crow0 = rb * 16 + kq * 4;

  // stage Whz(1), Whr(3), Whh(5) in fragment order (contiguous 1KB per wave read)
  for (int idx = tid; idx < 3 * 32 * 64; idx += 512){
    int mat = idx / (32 * 64), rem = idx % (32 * 64), kk5 = rem >> 6, ln = rem & 63;
    int n = ln & 15, kq2 = ln >> 4;
    *(short8*)&wl[(size_t)idx * 8] =
      *(const short8*)&wt[(size_t)(2 * mat + 1) * HID * HID +
                          (size_t)(wg * 16 + n) * HID + (size_t)(kk5 * 32 + kq2 * 8)];
  }
  for (int idx = tid; idx < BATCH * 16; idx += 512) hlds[idx] = 0.f;

  const unsigned short* wlg = wl + ((size_t)(zp ? 0 : 1) * 32 * 64 + lane) * 8;
  const unsigned short* wlh = wl + ((size_t)2 * 32 * 64 + lane) * 8;

  // A-operand fragment bases in fragment-major shared buffers (stride 2048 per 32-k)
  const unsigned short* hfr = hb2 + (size_t)arow * 8 + (size_t)kq * 512;
  const unsigned short* rfr = rh2 + (size_t)arow * 8 + (size_t)kq * 512;

  const bool evn = (l16 & 1) == 0;

  float h[4] = {0.f, 0.f, 0.f, 0.f};
  float gate[4];

  __syncthreads();

  for (int t = 0; t < T_STEPS; ++t){
    // ---- prefetch this step's precomputed x-gate values (independent of flags) ----
    float gx[4], gh[4];
    {
      const int g1 = zp ? 0 : 1;
      #pragma unroll
      for (int j = 0; j < 4; ++j){
        size_t base = (size_t)(t * BATCH + crow0 + j) * 3072 + col;
        gx[j] = b2f(G[base + g1 * 1024]);
        if (zp) gh[j] = b2f(G[base + 2 * 1024]);
      }
    }

    // ---- phase A: gates Z (zp) / R (rp) ----
    if (wave == 0 && t) waitflags(flags, 2 * t);
    __syncthreads();
    f32x4 a0 = {0.f,0.f,0.f,0.f}, a1 = {0.f,0.f,0.f,0.f};
    if (t){
      short8 hf[32];
      #pragma unroll
      for (int i = 0; i < 32; ++i) hf[i] = ldsc(hfr + (size_t)i * 2048);  // batch, ~1 RTT
      #pragma unroll
      for (int i = 0; i < 32; i += 2){
        a0 = MFMA(hf[i],     *(const short8*)(wlg + (size_t)i * 512),       a0, 0,0,0);
        a1 = MFMA(hf[i + 1], *(const short8*)(wlg + (size_t)(i + 1) * 512), a1, 0,0,0);
      }
    }
    if (zp){
      #pragma unroll
      for (int j = 0; j < 4; ++j) gate[j] = sigm(a0[j] + a1[j] + gx[j]);   // Z
    } else {
      #pragma unroll
      for (int j = 0; j < 4; ++j){
        float hp = hlds[(crow0 + j) * 16 + l16];
        unsigned v = f2b(sigm(a0[j] + a1[j] + gx[j]) * hp);                // R*H bf16
        unsigned o = __shfl_xor((int)v, 1);
        if (evn)
          __hip_atomic_store((unsigned*)&rh2[((size_t)(col >> 3) * 64 + crow0 + j) * 8 + (col & 7)],
                             v | (o << 16), __ATOMIC_RELAXED, __HIP_MEMORY_SCOPE_AGENT);
      }
    }
    __syncthreads();   // drains every wave's stores before leader releases
    if (tid == 0){
      asm volatile("s_waitcnt vmcnt(0)" ::: "memory");
      __hip_atomic_store(&flags[wg], 2 * t + 1, __ATOMIC_RELAXED, __HIP_MEMORY_SCOPE_AGENT);
    }

    // ---- phase B (zp waves): H_tilde + combine + publish H_t ----
    if (wave == 0) waitflags(flags, 2 * t + 1);
    __syncthreads();
    if (zp){
      f32x4 c0 = {0.f,0.f,0.f,0.f}, c1 = {0.f,0.f,0.f,0.f};
      short8 rf[32];
      #pragma unroll
      for (int i = 0; i < 32; ++i) rf[i] = ldsc(rfr + (size_t)i * 2048);
      #pragma unroll
      for (int i = 0; i < 32; i += 2){
        c0 = MFMA(rf[i],     *(const short8*)(wlh + (size_t)i * 512),       c0, 0,0,0);
        c1 = MFMA(rf[i + 1], *(const short8*)(wlh + (size_t)(i + 1) * 512), c1, 0,0,0);
      }
      #pragma unroll
      for (int j = 0; j < 4; ++j){
        float ht = tanh_fast(c0[j] + c1[j] + gh[j]);
        float hn = gate[j] * h[j] + (1.0f - gate[j]) * ht;
        h[j] = hn;
        hlds[(crow0 + j) * 16 + l16] = hn;
        unsigned v = (unsigned)f2b(hn);
        unsigned o = __shfl_xor((int)v, 1);
        if (evn)
          __hip_atomic_store((unsigned*)&hb2[((size_t)(col >> 3) * 64 + crow0 + j) * 8 + (col & 7)],
                             v | (o << 16), __ATOMIC_RELAXED, __HIP_MEMORY_SCOPE_AGENT);
      }
    }
    __syncthreads();
    if (tid == 0){
      asm volatile("s_waitcnt vmcnt(0)" ::: "memory");
      __hip_atomic_store(&flags[wg], 2 * t + 2, __ATOMIC_RELAXED, __HIP_MEMORY_SCOPE_AGENT);
    }
    if (zp){   // out stores off the critical path, never read by other WGs
      #pragma unroll
      for (int j = 0; j < 4; ++j){
        __builtin_nontemporal_store(h[j], &out[((size_t)t * BATCH + crow0 + j) * HID + col]);
        if (t == T_STEPS - 1)
          __builtin_nontemporal_store(h[j],
              &out[(size_t)T_STEPS * BATCH * HID + (size_t)(crow0 + j) * HID + col]);
      }
    }
  }
}

extern "C" void kernel_launch(void* const* d_in, const int* in_sizes, int n_in,
                              void* d_out, int out_size, void* d_ws, size_t ws_size,
                              hipStream_t stream){
  const float* inputs = (const float*)d_in[0];
  const float* W_xz = (const float*)d_in[1];
  const float* W_hz = (const float*)d_in[2];
  const float* b_z  = (const float*)d_in[3];
  const float* W_xr = (const float*)d_in[4];
  const float* W_hr = (const float*)d_in[5];
  const float* b_r  = (const float*)d_in[6];
  const float* W_xh = (const float*)d_in[7];
  const float* W_hh = (const float*)d_in[8];
  const float* b_h  = (const float*)d_in[9];
  float* out = (float*)d_out;

  char* ws = (char*)d_ws;
  int*            flags = (int*)ws;                                  // 256 B (pad 4 KiB)
  unsigned short* hb2   = (unsigned short*)(ws + 4096);              // 128 KiB
  unsigned short* rh2   = (unsigned short*)(ws + 4096 + 131072);     // 128 KiB
  unsigned short* wt    = (unsigned short*)(ws + 266240);            // 12 MiB
  unsigned short* G     = (unsigned short*)(ws + 266240 + 12582912); // 192 MiB (bf16 [32768][3072])
  // total ws needed: ~204 MB

  gru_init_k<<<1, 64, 0, stream>>>(flags);
  gru_prepw_k<<<dim3(32, 32, 6), dim3(32, 8), 0, stream>>>(W_xz, W_hz, W_xr, W_hr, W_xh, W_hh, wt);
  gru_xproj_k<<<dim3(512, 12), 256, 0, stream>>>(inputs, wt, b_z, b_r, b_h, G);
  gru_scan_k<<<NWG, 512, 0, stream>>>(G, wt, out, hb2, rh2, flags);
}